// Round 2
// baseline (300.032 us; speedup 1.0000x reference)
//
#include <hip/hip_runtime.h>

#define B_ROWS   16384
#define D_DIM    2048
#define L_LAYERS 6
#define THREADS  1024                     // 16 waves/block
#define WPB      (THREADS / 64)           // 16 waves
#define BLOCKS   (B_ROWS / WPB)           // 1024 blocks, ONE row per wave

// native 4-float vector for __builtin_nontemporal_store (HIP float4 is a
// class type the builtin rejects; layout is identical)
typedef float f32x4 __attribute__((ext_vector_type(4)));

// Exact algebra (unchanged): x_l = c_l*x0 + u_l, u_l = sum_{i<l} b_i,
//   c_{l+1} = c_l*(1 + x0.W_l) + u_l.W_l.
// Whole net = 6 dots/row + scalar recurrence + out = c*x0 + U.
//
// R3 restructure: occupancy was the bottleneck (16 waves/CU, pinned by BOTH
// LDS 57.9KB/8-wave-block AND 112 VGPRs from the 2-row x prefetch).
//  - 1024-thread blocks, 1 row/wave: LDS cost per wave halves -> 2 blocks/CU
//    = 32 waves/CU (HW max) if VGPRs allow.
//  - x prefetch is 32 regs (1 row); e[] moved to LDS; natural pressure ~60.
//  - __launch_bounds__(1024,7): VGPR cap 73 (>= 7 waves/SIMD = 28/CU) --
//    deliberately NOT 8: forcing a 64 cap caused scratch spill in R2.
//  - x loads issued at kernel entry: HBM latency hides under W/b staging
//    + barrier.
//  - out stored non-temporal (never re-read) to keep x resident in L3.
__global__ __launch_bounds__(THREADS, 7) void cross_net_kernel(
    const float* __restrict__ x,
    const float* __restrict__ W,
    const float* __restrict__ b,
    float* __restrict__ out)
{
    __shared__ float Wl[L_LAYERS][D_DIM];   // 48 KB
    __shared__ float Ul[D_DIM];             // 8 KB
    __shared__ float red[WPB][L_LAYERS];    // 384 B
    __shared__ float eL[L_LAYERS];          // 24 B

    const int t    = threadIdx.x;
    const int lane = t & 63;
    const int wid  = t >> 6;

    // ---- issue this wave's row loads FIRST: latency hides under setup ----
    const int gw   = blockIdx.x * WPB + wid;       // one row per wave
    const float* xr = x + (size_t)gw * D_DIM;
    const int eoff = lane * 4;                     // + j*256, j=0..7 covers 2048
    float4 xv[8];
    #pragma unroll
    for (int j = 0; j < 8; ++j) xv[j] = *(const float4*)(xr + j * 256 + eoff);

    // ---- stage W, U = sum b_i, e[l] = (sum_{i<l} b_i).W_l ----
    {
        const int base = t * 2;                    // 1024 threads x 2 = 2048
        float2 prefix = make_float2(0.f, 0.f);
        float e_red[L_LAYERS];
        #pragma unroll
        for (int l = 0; l < L_LAYERS; ++l) {
            const float2 wv = *(const float2*)(W + l * D_DIM + base);
            const float2 bv = *(const float2*)(b + l * D_DIM + base);
            e_red[l] = prefix.x * wv.x + prefix.y * wv.y;   // prefix BEFORE b_l
            prefix.x += bv.x; prefix.y += bv.y;
            *(float2*)&Wl[l][base] = wv;
        }
        *(float2*)&Ul[base] = prefix;
        #pragma unroll
        for (int l = 0; l < L_LAYERS; ++l) {
            float v = e_red[l];
            #pragma unroll
            for (int off = 32; off >= 1; off >>= 1) v += __shfl_xor(v, off, 64);
            if (lane == 0) red[wid][l] = v;
        }
    }
    __syncthreads();
    if (t < L_LAYERS) {                            // finalize e once per block
        float s = 0.f;
        #pragma unroll
        for (int w = 0; w < WPB; ++w) s += red[w][t];
        eL[t] = s;
    }
    __syncthreads();

    // ---- dots: p[l] = x_row . W_l  (x from regs, W from LDS) ----
    float p[L_LAYERS];
    #pragma unroll
    for (int l = 0; l < L_LAYERS; ++l) {
        float a = 0.f;
        #pragma unroll
        for (int j = 0; j < 8; ++j) {
            const float4 wv = *(const float4*)&Wl[l][j * 256 + eoff];
            a += xv[j].x * wv.x + xv[j].y * wv.y + xv[j].z * wv.z + xv[j].w * wv.w;
        }
        p[l] = a;
    }

    #pragma unroll
    for (int off = 32; off >= 1; off >>= 1) {
        #pragma unroll
        for (int l = 0; l < L_LAYERS; ++l)
            p[l] += __shfl_xor(p[l], off, 64);
    }

    // ---- scalar recurrence (wave-uniform e from LDS, broadcast reads) ----
    float c = 1.f;
    #pragma unroll
    for (int l = 0; l < L_LAYERS; ++l)
        c = c * (1.f + p[l]) + eL[l];

    // ---- output: out = c*x0 + U (non-temporal; out is never re-read) ----
    float* orow = out + (size_t)gw * D_DIM;
    #pragma unroll
    for (int j = 0; j < 8; ++j) {
        const float4 uv = *(const float4*)&Ul[j * 256 + eoff];
        f32x4 o;
        o.x = c * xv[j].x + uv.x; o.y = c * xv[j].y + uv.y;
        o.z = c * xv[j].z + uv.z; o.w = c * xv[j].w + uv.w;
        __builtin_nontemporal_store(o, (f32x4*)(orow + j * 256 + eoff));
    }
}

extern "C" void kernel_launch(void* const* d_in, const int* in_sizes, int n_in,
                              void* d_out, int out_size, void* d_ws, size_t ws_size,
                              hipStream_t stream) {
    (void)in_sizes; (void)n_in; (void)d_ws; (void)ws_size; (void)out_size;
    const float* x = (const float*)d_in[0];
    const float* W = (const float*)d_in[1];
    const float* b = (const float*)d_in[2];
    float* out = (float*)d_out;
    cross_net_kernel<<<dim3(BLOCKS), dim3(THREADS), 0, stream>>>(x, W, b, out);
}

// Round 3
// 251.717 us; speedup vs baseline: 1.1919x; 1.1919x over previous
//
#include <hip/hip_runtime.h>

#define B_ROWS   16384
#define D_DIM    2048
#define L_LAYERS 6

#define ROW_THREADS 256                   // 4 waves/block, 1 row/wave
#define ROW_WAVES   (ROW_THREADS / 64)
#define ROW_BLOCKS  (B_ROWS / ROW_WAVES)  // 4096
#define PRE_THREADS 1024
#define WS_FLOATS   (D_DIM + L_LAYERS)    // U[2048] + e[6] in workspace

typedef float f32x4 __attribute__((ext_vector_type(4)));

// Exact algebra: x_l = c_l*x0 + u_l, u_l = sum_{i<l} b_i,
//   c_{l+1} = c_l*(1 + x0.W_l) + u_l.W_l.
// Whole net = 6 dots/row + scalar recurrence + out = c*x0 + U.
//
// R4 restructure (post-mortem of R2 spill): 1024-thread blocks quantize
// occupancy in 16-wave steps -> only useful VGPR caps are 64 (spill cliff,
// hit it: VGPR=36 + 280MB scratch traffic) or 128 (no gain). Fix:
//  - W is a 48KB global constant read by every wave -> L2-resident, does
//    NOT need LDS. Drop W staging; LDS is only U (8KB).
//  - U/e are row-independent -> precompute ONCE in a tiny kernel into d_ws
//    instead of per-block (saves 4096 redundant stagings + the e-reduce).
//  - 256-thread blocks, 1 row/wave, no launch_bounds cap: natural VGPR
//    ~60-70, 28-32 waves/CU, no spill.

// ---- kernel A: U = sum_i b_i ; e[l] = (sum_{i<l} b_i) . W_l  (1 block) ----
__global__ __launch_bounds__(PRE_THREADS) void precompute_Ue(
    const float* __restrict__ W,
    const float* __restrict__ b,
    float* __restrict__ ws)
{
    __shared__ float red[PRE_THREADS / 64][L_LAYERS];
    const int t    = threadIdx.x;
    const int lane = t & 63;
    const int wid  = t >> 6;
    const int base = t * 2;                        // 1024 x 2 = 2048

    float2 prefix = make_float2(0.f, 0.f);
    float e_red[L_LAYERS];
    #pragma unroll
    for (int l = 0; l < L_LAYERS; ++l) {
        const float2 wv = *(const float2*)(W + l * D_DIM + base);
        const float2 bv = *(const float2*)(b + l * D_DIM + base);
        e_red[l] = prefix.x * wv.x + prefix.y * wv.y;   // prefix BEFORE b_l
        prefix.x += bv.x; prefix.y += bv.y;
    }
    *(float2*)(ws + base) = prefix;                // U
    #pragma unroll
    for (int l = 0; l < L_LAYERS; ++l) {
        float v = e_red[l];
        #pragma unroll
        for (int off = 32; off >= 1; off >>= 1) v += __shfl_xor(v, off, 64);
        if (lane == 0) red[wid][l] = v;
    }
    __syncthreads();
    if (t < L_LAYERS) {
        float s = 0.f;
        #pragma unroll
        for (int w = 0; w < PRE_THREADS / 64; ++w) s += red[w][t];
        ws[D_DIM + t] = s;                         // e[l]
    }
}

// ---- kernel B: one row per wave; W from L2, U from LDS ----
template <bool USE_WS>
__global__ __launch_bounds__(ROW_THREADS) void cross_rows(
    const float* __restrict__ x,
    const float* __restrict__ W,
    const float* __restrict__ b,
    const float* __restrict__ ws,
    float* __restrict__ out)
{
    __shared__ float Ul[D_DIM];                    // 8 KB
    __shared__ float eLs[L_LAYERS];
    __shared__ float red[ROW_WAVES][L_LAYERS];     // fallback only

    const int t    = threadIdx.x;
    const int lane = t & 63;
    const int wid  = t >> 6;

    if constexpr (USE_WS) {
        // stage U (8KB, L2/L3-hot) + e from workspace
        const int base = t * 8;                    // 256 x 8 = 2048
        *(float4*)&Ul[base]     = *(const float4*)(ws + base);
        *(float4*)&Ul[base + 4] = *(const float4*)(ws + base + 4);
        if (t < L_LAYERS) eLs[t] = ws[D_DIM + t];
        __syncthreads();
    } else {
        // fallback: compute U/e per block from W,b (correct without ws)
        const int base = t * 8;
        float4 p0 = make_float4(0.f, 0.f, 0.f, 0.f);
        float4 p1 = make_float4(0.f, 0.f, 0.f, 0.f);
        float e_red[L_LAYERS];
        #pragma unroll
        for (int l = 0; l < L_LAYERS; ++l) {
            const float4 w0 = *(const float4*)(W + l * D_DIM + base);
            const float4 w1 = *(const float4*)(W + l * D_DIM + base + 4);
            const float4 b0 = *(const float4*)(b + l * D_DIM + base);
            const float4 b1 = *(const float4*)(b + l * D_DIM + base + 4);
            e_red[l] = p0.x * w0.x + p0.y * w0.y + p0.z * w0.z + p0.w * w0.w
                     + p1.x * w1.x + p1.y * w1.y + p1.z * w1.z + p1.w * w1.w;
            p0.x += b0.x; p0.y += b0.y; p0.z += b0.z; p0.w += b0.w;
            p1.x += b1.x; p1.y += b1.y; p1.z += b1.z; p1.w += b1.w;
        }
        *(float4*)&Ul[base]     = p0;
        *(float4*)&Ul[base + 4] = p1;
        #pragma unroll
        for (int l = 0; l < L_LAYERS; ++l) {
            float v = e_red[l];
            #pragma unroll
            for (int off = 32; off >= 1; off >>= 1) v += __shfl_xor(v, off, 64);
            if (lane == 0) red[wid][l] = v;
        }
        __syncthreads();
        if (t < L_LAYERS) {
            float s = 0.f;
            #pragma unroll
            for (int w = 0; w < ROW_WAVES; ++w) s += red[w][t];
            eLs[t] = s;
        }
        __syncthreads();
    }

    // ---- row phase: barrier-free, one wave per row ----
    const int gw   = blockIdx.x * ROW_WAVES + wid;
    const float* xr = x + (size_t)gw * D_DIM;
    const int eoff = lane * 4;                     // + j*256, j=0..7

    float4 xv[8];
    #pragma unroll
    for (int j = 0; j < 8; ++j) xv[j] = *(const float4*)(xr + j * 256 + eoff);

    // dots vs W straight from global (48KB, L2-resident, coalesced 1KB/load)
    float p[L_LAYERS];
    #pragma unroll
    for (int l = 0; l < L_LAYERS; ++l) {
        float a = 0.f;
        #pragma unroll
        for (int j = 0; j < 8; ++j) {
            const float4 wv = *(const float4*)(W + l * D_DIM + j * 256 + eoff);
            a += xv[j].x * wv.x + xv[j].y * wv.y + xv[j].z * wv.z + xv[j].w * wv.w;
        }
        p[l] = a;
    }

    #pragma unroll
    for (int off = 32; off >= 1; off >>= 1) {
        #pragma unroll
        for (int l = 0; l < L_LAYERS; ++l)
            p[l] += __shfl_xor(p[l], off, 64);
    }

    float c = 1.f;
    #pragma unroll
    for (int l = 0; l < L_LAYERS; ++l)
        c = c * (1.f + p[l]) + eLs[l];             // broadcast LDS reads

    float* orow = out + (size_t)gw * D_DIM;
    #pragma unroll
    for (int j = 0; j < 8; ++j) {
        const float4 uv = *(const float4*)&Ul[j * 256 + eoff];
        f32x4 o;
        o.x = c * xv[j].x + uv.x; o.y = c * xv[j].y + uv.y;
        o.z = c * xv[j].z + uv.z; o.w = c * xv[j].w + uv.w;
        __builtin_nontemporal_store(o, (f32x4*)(orow + j * 256 + eoff));
    }
}

extern "C" void kernel_launch(void* const* d_in, const int* in_sizes, int n_in,
                              void* d_out, int out_size, void* d_ws, size_t ws_size,
                              hipStream_t stream) {
    (void)in_sizes; (void)n_in; (void)out_size;
    const float* x = (const float*)d_in[0];
    const float* W = (const float*)d_in[1];
    const float* b = (const float*)d_in[2];
    float* out = (float*)d_out;

    const bool use_ws = (d_ws != nullptr) && (ws_size >= WS_FLOATS * sizeof(float));
    if (use_ws) {
        float* ws = (float*)d_ws;
        precompute_Ue<<<dim3(1), dim3(PRE_THREADS), 0, stream>>>(W, b, ws);
        cross_rows<true><<<dim3(ROW_BLOCKS), dim3(ROW_THREADS), 0, stream>>>(
            x, W, b, ws, out);
    } else {
        cross_rows<false><<<dim3(ROW_BLOCKS), dim3(ROW_THREADS), 0, stream>>>(
            x, W, b, nullptr, out);
    }
}